// Round 4
// baseline (268.402 us; speedup 1.0000x reference)
//
#include <hip/hip_runtime.h>

#define T_DIM 2048
#define B_DIM 16
#define C_DIM 512
#define NW 56                         // H*K
#define ROWSTEP (B_DIM * C_DIM)       // floats between consecutive t rows

typedef __attribute__((ext_vector_type(8))) short short8;
typedef __attribute__((ext_vector_type(4))) float floatx4;

static __device__ __forceinline__ unsigned short f2bf(float x_) {
    union { float f; unsigned u; } v; v.f = x_;
    return (unsigned short)((v.u + 0x7FFFu + ((v.u >> 16) & 1u)) >> 16);  // RNE
}

// ---------------------------------------------------------------------------
// Pre-kernel: pack W (512x56 fp32) into bf16 MFMA B-fragments, HEAD-PACKED:
// n-tile nt covers global cols n = nt*14 + c, c in 0..13 (heads 2nt, 2nt+1);
// c = 14,15 zero-pad. Softmax groups of 7 stay inside one 16-col tile.
// Bg[(ks*4+nt)*64 + l][j] = W[k = ks*32+((l>>4)&3)*8+j][n], l&15 = c.
// (validated in previous round)
// ---------------------------------------------------------------------------
__global__ __launch_bounds__(256)
void pack_w(const float* __restrict__ W, short8* __restrict__ Bg) {
    const int g  = blockIdx.x * 256 + threadIdx.x;   // 0..4095
    const int ks = g >> 8;
    const int nt = (g >> 6) & 3;
    const int l  = g & 63;
    const int c  = l & 15;
    const int n  = nt * 14 + c;
    const int k0 = ks * 32 + ((l >> 4) & 3) * 8;
    short8 o;
#pragma unroll
    for (int j = 0; j < 8; ++j) {
        const float v = (c < 14) ? W[(size_t)(k0 + j) * NW + n] : 0.f;
        o[j] = (short)f2bf(v);
    }
    Bg[g] = o;
}

// ---------------------------------------------------------------------------
// Conv helpers: lane l, half par owns the 28 fp32 patch values
// f = 56*l + 28*par + [0,28) where patch[f] = x[t + (f>>9) - 3, b, f&511].
// Outputs: channels 8*l + 4*par + [0,4).
// ---------------------------------------------------------------------------
template<bool GUARD>
static __device__ __forceinline__ void load_half(
    float* pf, int m, const float* __restrict__ xb,
    const float* __restrict__ x, int t0, int tbase, int b,
    const int* offp, int lane) {
    const int par = m & 1;
    if (!GUARD) {
        const float* bm = xb + (size_t)(m >> 1) * ROWSTEP;
#pragma unroll
        for (int j = 0; j < 7; ++j)
            *(float4*)(pf + 4 * j) = *(const float4*)(bm + offp[par * 7 + j]);
    } else {
        const int tt = tbase + (m >> 1);
#pragma unroll
        for (int j = 0; j < 7; ++j) {
            const int f  = 56 * lane + 28 * par + 4 * j;
            const int kj = f >> 9;
            const int cj = f & 511;
            const int tp = t0 + tt + kj - 3;
            const int tc = min(max(tp, 0), T_DIM - 1);
            float4 v = *(const float4*)(x + ((size_t)tc * B_DIM + b) * C_DIM + cj);
            if (tp < 0 || tp >= T_DIM) v = make_float4(0.f, 0.f, 0.f, 0.f);
            *(float4*)(pf + 4 * j) = v;
        }
    }
}

static __device__ __forceinline__ void comp_half(
    const float* pf, int m, int tbase, const float* wtl,
    int t0, int b, float* __restrict__ out, int lane) {
    const int par = m & 1, tt = tbase + (m >> 1);
    const int h = lane >> 3;
    const float* wrow = wtl + tt * NW + h * 7;
    float wv[7];
#pragma unroll
    for (int k = 0; k < 7; ++k) wv[k] = wrow[k];
    float a[4];
#pragma unroll
    for (int r = 0; r < 4; ++r) {
        float s = pf[r * 7] * wv[0];
#pragma unroll
        for (int k = 1; k < 7; ++k) s = fmaf(wv[k], pf[r * 7 + k], s);
        a[r] = s;
    }
    const floatx4 v = (floatx4){a[0], a[1], a[2], a[3]};
    float* orow = out + ((size_t)(t0 + tt) * B_DIM + b) * C_DIM + lane * 8 + par * 4;
    __builtin_nontemporal_store(v, (floatx4*)orow);
}

template<bool GUARD>
static __device__ __forceinline__ void conv_pipeline(
    const float* __restrict__ x, float* __restrict__ out,
    const float* wtl, int t0, int b, int lane, int tbase) {
    int offp[14];
#pragma unroll
    for (int par = 0; par < 2; ++par)
#pragma unroll
        for (int j = 0; j < 7; ++j) {
            const int f = 56 * lane + 28 * par + 4 * j;
            offp[par * 7 + j] = (f >> 9) * ROWSTEP + (f & 511);
        }
    const float* xb = x + ((ptrdiff_t)(t0 + tbase - 3) * B_DIM + b) * C_DIM;

    float pA[28], pB[28];
    // prefetch first half before the barrier (hides wt/LDS latency)
    load_half<GUARD>(pA, 0, xb, x, t0, tbase, b, offp, lane);
    __syncthreads();      // wt published by both waves
#pragma unroll
    for (int m = 0; m < 16; m += 2) {
        load_half<GUARD>(pB, m + 1, xb, x, t0, tbase, b, offp, lane);
        comp_half(pA, m, tbase, wtl, t0, b, out, lane);
        if (m + 2 < 16)
            load_half<GUARD>(pA, m + 2, xb, x, t0, tbase, b, offp, lane);
        comp_half(pB, m + 1, tbase, wtl, t0, b, out, lane);
    }
}

// ---------------------------------------------------------------------------
// Fused kernel, 2 waves/block, one 2-wave barrier, LDS = 3.5 KB (wt only).
// Wave w: GEMM chains nt = {2w, 2w+1} (A tile loaded once, 64 VGPR),
// in-wave softmax -> wt LDS; barrier; conv rows tt in [8w, 8w+8) with
// register ping-pong, x read directly from global in fp32.
// Grid 2048 x 128 thr -> 16 waves/CU, all resident (one round, no tail).
// ---------------------------------------------------------------------------
__global__ __launch_bounds__(128, 4)
void fused2(const float* __restrict__ x, const float* __restrict__ q,
            const short8* __restrict__ Bg, float* __restrict__ out) {
    __shared__ __align__(16) float wtl[16 * NW];

    const int tid  = threadIdx.x;
    const int lane = tid & 63;
    const int w    = tid >> 6;                 // wave id 0..1
    const int b    = blockIdx.x & 15;
    const int t0   = (blockIdx.x >> 4) * 16;

    // ---- A fragments: lane (rq,qq) loads 8 bf16 per ks, all 16 ks
    const int rq = lane & 15;                  // A row (= t within tile)
    const int qq = lane >> 4;                  // quad -> k sub-offset
    const float* qbase = q + ((size_t)(t0 + rq) * B_DIM + b) * C_DIM + qq * 8;
    short8 A[16];
#pragma unroll
    for (int ks = 0; ks < 16; ++ks) {
        const float4 f0 = *(const float4*)(qbase + ks * 32);
        const float4 f1 = *(const float4*)(qbase + ks * 32 + 4);
        short8 af;
        af[0] = (short)f2bf(f0.x); af[1] = (short)f2bf(f0.y);
        af[2] = (short)f2bf(f0.z); af[3] = (short)f2bf(f0.w);
        af[4] = (short)f2bf(f1.x); af[5] = (short)f2bf(f1.y);
        af[6] = (short)f2bf(f1.z); af[7] = (short)f2bf(f1.w);
        A[ks] = af;
    }

    // ---- two MFMA chains + in-wave softmax (head-packed cols)
    const int c    = lane & 15;
    const int cb   = (c < 7) ? 0 : 7;
    const int sb   = (lane & 48) + cb;
    const int quad = lane >> 4;
#pragma unroll
    for (int ccn = 0; ccn < 2; ++ccn) {
        const int nt = w * 2 + ccn;
        floatx4 acc = (floatx4){0.f, 0.f, 0.f, 0.f};
#pragma unroll 4
        for (int ks = 0; ks < 16; ++ks) {
            const short8 bf = Bg[(ks * 4 + nt) * 64 + lane];
            acc = __builtin_amdgcn_mfma_f32_16x16x32_bf16(A[ks], bf, acc, 0, 0, 0);
        }
#pragma unroll
        for (int r = 0; r < 4; ++r) {
            const float a = acc[r];
            const float v0 = __shfl(a, sb + 0);
            const float v1 = __shfl(a, sb + 1);
            const float v2 = __shfl(a, sb + 2);
            const float v3 = __shfl(a, sb + 3);
            const float v4 = __shfl(a, sb + 4);
            const float v5 = __shfl(a, sb + 5);
            const float v6 = __shfl(a, sb + 6);
            const float mx = fmaxf(fmaxf(fmaxf(v0, v1), fmaxf(v2, v3)),
                                   fmaxf(fmaxf(v4, v5), v6));
            const float sm = __expf(v0 - mx) + __expf(v1 - mx) + __expf(v2 - mx) +
                             __expf(v3 - mx) + __expf(v4 - mx) + __expf(v5 - mx) +
                             __expf(v6 - mx);
            const float wres = __expf(a - mx) * (1.0f / sm);
            if (c < 14)
                wtl[(quad * 4 + r) * NW + nt * 14 + c] = wres;
        }
    }

    // ---- conv: wave w owns rows tt in [8w, 8w+8)
    const int tbase = w * 8;
    if (t0 >= 16 && t0 <= T_DIM - 32)
        conv_pipeline<false>(x, out, wtl, t0, b, lane, tbase);
    else
        conv_pipeline<true>(x, out, wtl, t0, b, lane, tbase);
}

extern "C" void kernel_launch(void* const* d_in, const int* in_sizes, int n_in,
                              void* d_out, int out_size, void* d_ws, size_t ws_size,
                              hipStream_t stream) {
    const float* x = (const float*)d_in[0];
    const float* q = (const float*)d_in[1];
    const float* W = (const float*)d_in[2];
    float* out = (float*)d_out;
    short8* Bg = (short8*)d_ws;   // 64 KB packed bf16 B-fragments (head-packed)

    pack_w<<<16, 256, 0, stream>>>(W, Bg);
    fused2<<<(T_DIM / 16) * B_DIM, 128, 0, stream>>>(x, q, Bg, out);
}

// Round 5
// 183.758 us; speedup vs baseline: 1.4606x; 1.4606x over previous
//
#include <hip/hip_runtime.h>

#define T_DIM 2048
#define B_DIM 16
#define C_DIM 512
#define NW 56                         // H*K

// ---- conv LDS map: xs (bf16 22x512, swizzled) + wt (fp32 16x56)
#define XS_BYTES (22 * 512 * 2)       // 22528 B
#define C_WT_OFF XS_BYTES
#define C_LDS    (XS_BYTES + 3584)    // 26112 B; 512 thr -> 4 blocks/CU = 32 waves

typedef __attribute__((ext_vector_type(8))) short short8;
typedef __attribute__((ext_vector_type(4))) float floatx4;

static __device__ __forceinline__ unsigned short f2bf(float x_) {
    union { float f; unsigned u; } v; v.f = x_;
    return (unsigned short)((v.u + 0x7FFFu + ((v.u >> 16) & 1u)) >> 16);  // RNE
}
static __device__ __forceinline__ float bf_lo(unsigned u) {
    union { unsigned u; float f; } c; c.u = u << 16; return c.f;
}
static __device__ __forceinline__ float bf_hi(unsigned u) {
    union { unsigned u; float f; } c; c.u = u & 0xFFFF0000u; return c.f;
}
// 16B-block XOR swizzle for the bf16 xs layout: bank-group bits [6:4] ^= addr[9:7].
// Conv read pattern (lane stride 112 B) lands all 64 lanes on distinct groups.
static __device__ __forceinline__ int swz(int a) { return a ^ ((a >> 3) & 0x70); }

// ---------------------------------------------------------------------------
// Pre-kernel: pack W (512x56 fp32) into bf16 MFMA B-fragments, HEAD-PACKED:
// n-tile nt covers global cols n = nt*14 + c, c in 0..13 (heads 2nt, 2nt+1);
// c = 14,15 zero-pad. Head-packed col index equals the global flat n, so the
// softmax group of 7 lives inside one wave's 16-col tile.
// Bg[(ks*4+nt)*64 + l][j] = W[k = ks*32+((l>>4)&3)*8+j][n], l&15 = c.
// ---------------------------------------------------------------------------
__global__ __launch_bounds__(256)
void pack_w(const float* __restrict__ W, short8* __restrict__ Bg) {
    const int g  = blockIdx.x * 256 + threadIdx.x;   // 0..4095
    const int ks = g >> 8;
    const int nt = (g >> 6) & 3;
    const int l  = g & 63;
    const int c  = l & 15;
    const int n  = nt * 14 + c;
    const int k0 = ks * 32 + ((l >> 4) & 3) * 8;
    short8 o;
#pragma unroll
    for (int j = 0; j < 8; ++j) {
        const float v = (c < 14) ? W[(size_t)(k0 + j) * NW + n] : 0.f;
        o[j] = (short)f2bf(v);
    }
    Bg[g] = o;
}

// ---------------------------------------------------------------------------
// Kernel W: logits GEMM + in-wave softmax -> wt_g (fp32, global).
// Block = 16 t x 1 b, 4 waves; wave wv owns n-tile wv (heads 2wv, 2wv+1).
// ONE barrier (A8 staging). B frags rolled from global (L2-hot, low VGPR).
// Softmax entirely in-wave via shfl over the head-packed 16-col tile; weights
// stored straight to global (7 MB total) -- no L tile, no wt LDS, no extra
// barriers.
// ---------------------------------------------------------------------------
__global__ __launch_bounds__(256)
void weight2(const float* __restrict__ q, const short8* __restrict__ Bg,
             float* __restrict__ wt_g) {
    __shared__ __align__(16) short8 A8[16 * 64];   // 16384 B

    const int tid  = threadIdx.x;
    const int lane = tid & 63;
    const int wv   = tid >> 6;                 // wave id = n-tile
    const int b    = blockIdx.x & 15;
    const int t0   = (blockIdx.x >> 4) * 16;

    // stage A tile in fragment order (coalesced q read, once per block)
    const int rq = lane & 15;                  // A row (= t within tile)
    const int qq = lane >> 4;                  // quad -> k sub-offset
    const float* qrow = q + ((size_t)(t0 + rq) * B_DIM + b) * C_DIM + qq * 8;
#pragma unroll
    for (int s = 0; s < 4; ++s) {
        const int ks = wv + s * 4;
        const float4 f0 = *(const float4*)(qrow + ks * 32);
        const float4 f1 = *(const float4*)(qrow + ks * 32 + 4);
        short8 o;
        o[0] = (short)f2bf(f0.x); o[1] = (short)f2bf(f0.y);
        o[2] = (short)f2bf(f0.z); o[3] = (short)f2bf(f0.w);
        o[4] = (short)f2bf(f1.x); o[5] = (short)f2bf(f1.y);
        o[6] = (short)f2bf(f1.z); o[7] = (short)f2bf(f1.w);
        A8[ks * 64 + lane] = o;
    }
    __syncthreads();

    // GEMM: 16 MFMAs, B frags rolled from global (L2-hot)
    floatx4 acc = (floatx4){0.f, 0.f, 0.f, 0.f};
#pragma unroll
    for (int ks = 0; ks < 16; ++ks) {
        const short8 bf = Bg[(ks * 4 + wv) * 64 + lane];
        acc = __builtin_amdgcn_mfma_f32_16x16x32_bf16(A8[ks * 64 + lane], bf,
                                                      acc, 0, 0, 0);
    }

    // in-wave softmax over groups of 7 (head-packed cols), direct global store
    const int c    = lane & 15;
    const int cb   = (c < 7) ? 0 : 7;
    const int sb   = (lane & 48) + cb;
    const int quad = lane >> 4;
#pragma unroll
    for (int r = 0; r < 4; ++r) {
        const float a = acc[r];
        const float v0 = __shfl(a, sb + 0);
        const float v1 = __shfl(a, sb + 1);
        const float v2 = __shfl(a, sb + 2);
        const float v3 = __shfl(a, sb + 3);
        const float v4 = __shfl(a, sb + 4);
        const float v5 = __shfl(a, sb + 5);
        const float v6 = __shfl(a, sb + 6);
        const float mx = fmaxf(fmaxf(fmaxf(v0, v1), fmaxf(v2, v3)),
                               fmaxf(fmaxf(v4, v5), v6));
        const float sm = __expf(v0 - mx) + __expf(v1 - mx) + __expf(v2 - mx) +
                         __expf(v3 - mx) + __expf(v4 - mx) + __expf(v5 - mx) +
                         __expf(v6 - mx);
        const float w = __expf(a - mx) * (1.0f / sm);
        if (c < 14)
            wt_g[((size_t)(t0 + quad * 4 + r) * B_DIM + b) * NW + wv * 14 + c] = w;
    }
}

// ---------------------------------------------------------------------------
// Kernel C: conv with precomputed weights. Block = 16 t x 1 b, 512 threads
// (8 waves), ONE barrier. 26112 B LDS -> 4 blocks/CU = 32 waves (100% cap).
// Wave wv owns rows tt = wv*2 + s, s in {0,1}.
// ---------------------------------------------------------------------------
__global__ __launch_bounds__(512)
void conv2(const float* __restrict__ x, const float* __restrict__ wt_g,
           float* __restrict__ out) {
    __shared__ __align__(16) char S[C_LDS];

    const int tid  = threadIdx.x;
    const int lane = tid & 63;
    const int wv   = tid >> 6;                 // 0..7
    const int b    = blockIdx.x & 15;
    const int t0   = (blockIdx.x >> 4) * 16;

    // issue x-window loads (22 padded rows x 512 fp32 = 2816 float4)
    float4 xr[6];
#pragma unroll
    for (int j = 0; j < 6; ++j) {
        const int idx = tid + j * 512;
        xr[j] = make_float4(0.f, 0.f, 0.f, 0.f);
        if (idx < 2816) {
            const int i  = idx >> 7;           // padded row 0..21
            const int cc = (idx & 127) * 4;
            const int tp = t0 + i - 3;
            if (tp >= 0 && tp < T_DIM)
                xr[j] = *(const float4*)(x + ((size_t)tp * B_DIM + b) * C_DIM + cc);
        }
    }
    // issue wt load (224 float4)
    float4 wld = make_float4(0.f, 0.f, 0.f, 0.f);
    const int wrow = tid / 14;
    const int wj   = tid - wrow * 14;
    if (tid < 224)
        wld = *(const float4*)(wt_g + ((size_t)(t0 + wrow) * B_DIM + b) * NW + wj * 4);

    // convert x -> bf16 xs (swizzled), stage wt
    char* XS = S;
#pragma unroll
    for (int j = 0; j < 6; ++j) {
        const int idx = tid + j * 512;
        if (idx < 2816) {
            uint2 p;
            p.x = (unsigned)f2bf(xr[j].x) | ((unsigned)f2bf(xr[j].y) << 16);
            p.y = (unsigned)f2bf(xr[j].z) | ((unsigned)f2bf(xr[j].w) << 16);
            *(uint2*)(XS + swz(idx * 8)) = p;
        }
    }
    if (tid < 224)
        *(float4*)(S + C_WT_OFF + (wrow * NW + wj * 4) * 4) = wld;
    __syncthreads();

    // conv: lane owns outputs 8l..8l+8 = window bytes [112l, 112l+112)
    const float* wt = (const float*)(S + C_WT_OFF);
    const int h = lane >> 3;
    const int base_b = lane * 112;
#pragma unroll
    for (int s = 0; s < 2; ++s) {
        const int tt = wv * 2 + s;
        const int tb = tt * 1024 + base_b;
        uint4 xu[7];
#pragma unroll
        for (int i = 0; i < 7; ++i)
            xu[i] = *(const uint4*)(XS + swz(tb + i * 16));
        float xf[56];
#pragma unroll
        for (int i = 0; i < 7; ++i) {
            xf[i * 8 + 0] = bf_lo(xu[i].x); xf[i * 8 + 1] = bf_hi(xu[i].x);
            xf[i * 8 + 2] = bf_lo(xu[i].y); xf[i * 8 + 3] = bf_hi(xu[i].y);
            xf[i * 8 + 4] = bf_lo(xu[i].z); xf[i * 8 + 5] = bf_hi(xu[i].z);
            xf[i * 8 + 6] = bf_lo(xu[i].w); xf[i * 8 + 7] = bf_hi(xu[i].w);
        }
        const float* wp = wt + tt * NW + h * 7;
        float w[7];
#pragma unroll
        for (int k = 0; k < 7; ++k) w[k] = wp[k];
        float a8[8];
#pragma unroll
        for (int r = 0; r < 8; ++r) {
            float sacc = xf[r * 7] * w[0];
#pragma unroll
            for (int k = 1; k < 7; ++k) sacc = fmaf(w[k], xf[r * 7 + k], sacc);
            a8[r] = sacc;
        }
        float* orow = out + ((size_t)(t0 + tt) * B_DIM + b) * C_DIM + lane * 8;
        const floatx4 v0 = (floatx4){a8[0], a8[1], a8[2], a8[3]};
        const floatx4 v1 = (floatx4){a8[4], a8[5], a8[6], a8[7]};
        __builtin_nontemporal_store(v0, (floatx4*)orow);
        __builtin_nontemporal_store(v1, (floatx4*)(orow + 4));
    }
}

extern "C" void kernel_launch(void* const* d_in, const int* in_sizes, int n_in,
                              void* d_out, int out_size, void* d_ws, size_t ws_size,
                              hipStream_t stream) {
    const float* x = (const float*)d_in[0];
    const float* q = (const float*)d_in[1];
    const float* W = (const float*)d_in[2];
    float* out = (float*)d_out;
    short8* Bg  = (short8*)d_ws;                       // 64 KB packed B-fragments
    float* wt_g = (float*)((char*)d_ws + 65536);       // 7.34 MB weights

    pack_w<<<16, 256, 0, stream>>>(W, Bg);
    weight2<<<(T_DIM / 16) * B_DIM, 256, 0, stream>>>(q, Bg, wt_g);
    conv2<<<(T_DIM / 16) * B_DIM, 512, 0, stream>>>(x, wt_g, out);
}